// Round 1
// baseline (198.384 us; speedup 1.0000x reference)
//
#include <hip/hip_runtime.h>

// Problem constants (from reference):
//   x: (32, 1024, 1024) f32; segment_ids: (32, 1024) int (cast to int32 per harness)
//   lo=257, hi=769 -> 512 tokens/batch, 16384 tokens total
//   out: (2048, 2048) f32 = per-segment mean of [x[b,257+t,:1024] ++ x[b,0,:1024]]
#define NBATCH 32
#define TOK 512
#define NTOK (NBATCH * TOK)      // 16384
#define NSEG 2048
#define LO 257
#define XROW 1024                // floats per x row
#define XBATCH (1024 * 1024)     // floats per batch of x
#define SEGROW 1024              // segment_ids row length

__global__ void k_zero(int* __restrict__ counts, int* __restrict__ cursor) {
    int i = blockIdx.x * blockDim.x + threadIdx.x;
    if (i < NSEG) { counts[i] = 0; cursor[i] = 0; }
}

__global__ void k_count(const int* __restrict__ seg_ids, int* __restrict__ counts) {
    int i = blockIdx.x * blockDim.x + threadIdx.x;  // token 0..16383
    int b = i >> 9, t = i & 511;
    int s = seg_ids[b * SEGROW + LO + t];
    if (s >= 0) atomicAdd(&counts[s], 1);
}

// Exclusive prefix sum over 2048 counts -> offsets[0..2048]
__global__ void k_scan(const int* __restrict__ counts, int* __restrict__ offsets) {
    __shared__ int chunk[256];
    int tid = threadIdx.x;
    int base = tid * 8;
    int local[8];
    int sum = 0;
#pragma unroll
    for (int j = 0; j < 8; j++) { local[j] = sum; sum += counts[base + j]; }
    chunk[tid] = sum;
    __syncthreads();
    if (tid == 0) {
        int acc = 0;
        for (int i = 0; i < 256; i++) { int c = chunk[i]; chunk[i] = acc; acc += c; }
        offsets[NSEG] = acc;
    }
    __syncthreads();
    int cb = chunk[tid];
#pragma unroll
    for (int j = 0; j < 8; j++) offsets[base + j] = cb + local[j];
}

__global__ void k_fill(const int* __restrict__ seg_ids, const int* __restrict__ offsets,
                       int* __restrict__ cursor, int* __restrict__ list) {
    int i = blockIdx.x * blockDim.x + threadIdx.x;
    int b = i >> 9, t = i & 511;
    int s = seg_ids[b * SEGROW + LO + t];
    if (s >= 0) {
        int pos = atomicAdd(&cursor[s], 1);
        list[offsets[s] + pos] = i;
    }
}

// One block per segment; thread tid owns float4 [tid*4 .. tid*4+3] of each half.
__global__ __launch_bounds__(256) void k_main(const float* __restrict__ x,
                                              const int* __restrict__ offsets,
                                              const int* __restrict__ list,
                                              float* __restrict__ out) {
    int seg = blockIdx.x;
    int tid = threadIdx.x;
    int start = offsets[seg], end = offsets[seg + 1];
    int n = end - start;

    float4 a1 = make_float4(0.f, 0.f, 0.f, 0.f);  // emb half
    float4 a2 = make_float4(0.f, 0.f, 0.f, 0.f);  // cls half
    for (int i = start; i < end; i++) {
        int id = list[i];
        int b = id >> 9, t = id & 511;
        const float4* emb = (const float4*)(x + (size_t)b * XBATCH + (size_t)(LO + t) * XROW);
        const float4* cls = (const float4*)(x + (size_t)b * XBATCH);
        float4 e = emb[tid];
        float4 c = cls[tid];
        a1.x += e.x; a1.y += e.y; a1.z += e.z; a1.w += e.w;
        a2.x += c.x; a2.y += c.y; a2.z += c.z; a2.w += c.w;
    }
    float inv = 1.0f / (float)(n > 0 ? n : 1);
    a1.x *= inv; a1.y *= inv; a1.z *= inv; a1.w *= inv;
    a2.x *= inv; a2.y *= inv; a2.z *= inv; a2.w *= inv;

    float4* o = (float4*)(out + (size_t)seg * 2048);
    o[tid] = a1;            // features 0..1023
    o[256 + tid] = a2;      // features 1024..2047
}

extern "C" void kernel_launch(void* const* d_in, const int* in_sizes, int n_in,
                              void* d_out, int out_size, void* d_ws, size_t ws_size,
                              hipStream_t stream) {
    const float* x = (const float*)d_in[0];
    const int* seg_ids = (const int*)d_in[1];
    float* out = (float*)d_out;

    int* ws = (int*)d_ws;
    int* counts  = ws;            // 2048
    int* cursor  = ws + 2048;     // 2048
    int* offsets = ws + 4096;     // 2049
    int* list    = ws + 8192;     // 16384

    k_zero<<<(NSEG + 255) / 256, 256, 0, stream>>>(counts, cursor);
    k_count<<<NTOK / 256, 256, 0, stream>>>(seg_ids, counts);
    k_scan<<<1, 256, 0, stream>>>(counts, offsets);
    k_fill<<<NTOK / 256, 256, 0, stream>>>(seg_ids, offsets, cursor, list);
    k_main<<<NSEG, 256, 0, stream>>>(x, offsets, list, out);
}